// Round 19
// baseline (1026.811 us; speedup 1.0000x reference)
//
#include <hip/hip_runtime.h>
#include <cstdint>
#include <cstddef>

#define HID 128
#define INC 256
#define NLAYER 3
#define SLOTS 96
#define P2G 16            // partial-reduction groups

static constexpr float EPS = 1e-5f;

typedef __attribute__((ext_vector_type(8))) short s16x8;
typedef __attribute__((ext_vector_type(4))) unsigned short us16x4;
typedef __attribute__((ext_vector_type(4))) float f32x4;
typedef __attribute__((ext_vector_type(2))) float f32x2;

__device__ __forceinline__ float eluf(float x) { return x > 0.f ? x : expm1f(x); }

__device__ __forceinline__ unsigned short f2bf(float x)
{
    unsigned u = __float_as_uint(x);
    u += 0x7FFFu + ((u >> 16) & 1u);
    return (unsigned short)(u >> 16);
}

__device__ __forceinline__ float bf2f(unsigned short u)
{
    return __uint_as_float(((unsigned)u) << 16);
}

__device__ __forceinline__ unsigned char f2fp8(float x)
{
    return (unsigned char)(__builtin_amdgcn_cvt_pk_fp8_f32(x, x, 0, false) & 0xFF);
}

// ---- CSR co-run side-job: blocks past hostGrid fill an edge range ----------
__device__ __forceinline__ bool csr_side(int hostGrid, const int* __restrict__ ei,
                                         int* cnt, int* crow, int Etot, int e0, int e1)
{
    if ((int)blockIdx.x < hostGrid) return false;
    int e = e0 + (int)(blockIdx.x - hostGrid) * 256 + (int)threadIdx.x;
    if (e < e1) {
        int r = ei[e], c = ei[Etot + e];
        int p = atomicAdd(&cnt[c], 1);
        if (p < SLOTS) crow[(size_t)c * SLOTS + p] = r;
    }
    return true;
}

// ---------------------------------------------------------------------------
// MLP GEMM, hi-only bf16 (R16 structure): C16 = bf16(ELU(BN(A @ W + bias))).
// ---------------------------------------------------------------------------
template<int K, bool IN32>
__global__ __launch_bounds__(256) void gemm_mlp(
    const float* __restrict__ Af, const unsigned short* __restrict__ A16,
    const unsigned short* __restrict__ Wth,
    const float* __restrict__ bias,
    const float* __restrict__ bng, const float* __restrict__ bnb,
    const float* __restrict__ bnm, const float* __restrict__ bnv,
    unsigned short* __restrict__ C16, int n,
    const int* __restrict__ ei, int* cntp, int* crowp, int Etot, int e0, int e1,
    int hostGrid)
{
    if (csr_side(hostGrid, ei, cntp, crowp, Etot, e0, e1)) return;

    __shared__ unsigned short Ah[64 * 64], Wh[128 * 64];
    const int t = threadIdx.x;
    const int l = t & 63;
    const int w = t >> 6;
    const int l15 = l & 15;
    const int row0 = blockIdx.x * 64;

    char* cAh = (char*)Ah;
    char* cWh = (char*)Wh;

    f32x4 acc[8] = {};

    for (int kc = 0; kc < K; kc += 64) {
        if (IN32) {
            #pragma unroll
            for (int i = 0; i < 4; ++i) {
                int f = t + 256 * i;
                int r = f >> 4, c4 = f & 15;
                int gr = row0 + r; if (gr > n - 1) gr = n - 1;
                float4 a4 = *(const float4*)&Af[(size_t)gr * K + kc + c4 * 4];
                int byte = r * 128 + (((c4 >> 1) * 16) ^ ((r & 7) << 4)) + (c4 & 1) * 8;
                *(us16x4*)(cAh + byte) =
                    (us16x4){f2bf(a4.x), f2bf(a4.y), f2bf(a4.z), f2bf(a4.w)};
            }
        } else {
            #pragma unroll
            for (int i = 0; i < 2; ++i) {
                int f = t + 256 * i;
                int r = f >> 3, c8 = f & 7;
                int gr = row0 + r; if (gr > n - 1) gr = n - 1;
                int byte = r * 128 + ((c8 * 16) ^ ((r & 7) << 4));
                *(s16x8*)(cAh + byte) = *(const s16x8*)&A16[(size_t)gr * K + kc + c8 * 8];
            }
        }
        #pragma unroll
        for (int i = 0; i < 4; ++i) {
            int f = t + 256 * i;
            int nr = f >> 3, c8 = f & 7;
            size_t gsrc = (size_t)nr * K + kc + c8 * 8;
            int byte = nr * 128 + ((c8 * 16) ^ ((nr & 7) << 4));
            *(s16x8*)(cWh + byte) = *(const s16x8*)&Wth[gsrc];
        }
        __syncthreads();
        #pragma unroll
        for (int ks = 0; ks < 2; ++ks) {
            int jA = ks * 4 + (l >> 4);
            int ar = w * 16 + l15;
            int aoff = ar * 128 + ((jA * 16) ^ ((ar & 7) << 4));
            s16x8 fah = *(s16x8*)(cAh + aoff);
            #pragma unroll
            for (int nt = 0; nt < 8; ++nt) {
                int nr = nt * 16 + l15;
                int boff = nr * 128 + ((jA * 16) ^ ((nr & 7) << 4));
                acc[nt] = __builtin_amdgcn_mfma_f32_16x16x32_bf16(fah, *(s16x8*)(cWh + boff), acc[nt], 0, 0, 0);
            }
        }
        __syncthreads();
    }

    const int rbase = row0 + w * 16 + ((l >> 4) << 2);
    #pragma unroll
    for (int nt = 0; nt < 8; ++nt) {
        int col = nt * 16 + l15;
        float bb = bias[col];
        float gm = bng[col], bt = bnb[col], mn = bnm[col], vr = bnv[col];
        #pragma unroll
        for (int r = 0; r < 4; ++r) {
            int row = rbase + r;
            if (row < n) {
                float o = acc[nt][r] + bb;
                o = eluf((o - mn) * rsqrtf(vr + EPS) * gm + bt);
                C16[(size_t)row * HID + col] = f2bf(o);
            }
        }
    }
}

// ---------------------------------------------------------------------------
// Fused per-layer QKVGR + kvs, W read DIRECTLY from global (L1/L2-resident,
// contiguous 16B fragments) — no cW stage, no in-loop barriers.
// LDS 32KB ([A/knT 16K][vT 16K]) -> 4 blocks/CU (16 waves).
// ---------------------------------------------------------------------------
struct QKVGRArgs {
    const unsigned short* wh[5];
    const float* bias[5];
};

__global__ __launch_bounds__(256) void fused_qkvgr(
    const unsigned short* __restrict__ A16, QKVGRArgs ar,
    unsigned short* __restrict__ qb16,
    unsigned char* __restrict__ gb8, float* __restrict__ accout,
    unsigned short* __restrict__ partial, int n,
    const int* __restrict__ ei, int* cntp, int* crowp, int Etot, int e0, int e1,
    int hostGrid)
{
    if (csr_side(hostGrid, ei, cntp, crowp, Etot, e0, e1)) return;

    __shared__ char smem[32768];
    char* cA  = smem;             // 16KB: staged h; becomes knT after m=1
    char* cVT = smem + 16384;     // 16KB: vT

    const int t = threadIdx.x;
    const int l = t & 63;
    const int w = t >> 6;
    const int l15 = l & 15;
    const int row0 = blockIdx.x * 64;

    // ---- stage A (bf16, swizzled, row stride 256B) ----
    #pragma unroll
    for (int i = 0; i < 4; ++i) {
        int f = t + 256 * i;
        int r = f >> 4, c8 = f & 15;
        int gr = row0 + r; if (gr > n - 1) gr = n - 1;
        int byte = r * 256 + ((c8 * 16) ^ ((r & 7) << 4));
        *(s16x8*)(cA + byte) = *(const s16x8*)&A16[(size_t)gr * HID + c8 * 8];
    }
    __syncthreads();

    s16x8 fah[4];
    {
        const int arow = w * 16 + l15;
        #pragma unroll
        for (int ks = 0; ks < 4; ++ks) {
            int aoff = arow * 256 + (((ks * 64) + (l >> 4) * 16) ^ ((arow & 7) << 4));
            fah[ks] = *(s16x8*)(cA + aoff);
        }
    }
    __syncthreads();   // all frags in regs before cA is reused at m=1

    const int rbase = row0 + w * 16 + ((l >> 4) << 2);
    const int rtb   = w * 16 + ((l >> 4) << 2);
    const int fco   = (l >> 4) * 8;          // fragment k-offset (elements)
    float skred[8], svred[8];

    for (int m = 0; m < 5; ++m) {
        const unsigned short* wh = ar.wh[m];

        f32x4 acc[8] = {};
        #pragma unroll
        for (int ks = 0; ks < 4; ++ks) {
            #pragma unroll
            for (int nt = 0; nt < 8; ++nt) {
                int nr = nt * 16 + l15;
                s16x8 fb = *(const s16x8*)&wh[(size_t)nr * HID + ks * 32 + fco];
                acc[nt] = __builtin_amdgcn_mfma_f32_16x16x32_bf16(fah[ks], fb, acc[nt], 0, 0, 0);
            }
        }

        float bb[8];
        #pragma unroll
        for (int nt = 0; nt < 8; ++nt) bb[nt] = ar.bias[m][nt * 16 + l15];

        if (m <= 1) {                       // q / k: bias + row L2 normalize
            float sk8[8] = {};
            #pragma unroll
            for (int r = 0; r < 4; ++r) {
                float ss = 0.f;
                #pragma unroll
                for (int nt = 0; nt < 8; ++nt) {
                    float o = acc[nt][r] + bb[nt];
                    ss += o * o;
                }
                ss += __shfl_xor(ss, 1); ss += __shfl_xor(ss, 2);
                ss += __shfl_xor(ss, 4); ss += __shfl_xor(ss, 8);
                float rn = rsqrtf(ss);
                int row = rbase + r;
                if (m == 0) {
                    if (row < n) {
                        #pragma unroll
                        for (int nt = 0; nt < 8; ++nt)
                            qb16[(size_t)row * HID + nt * 16 + l15] = f2bf((acc[nt][r] + bb[nt]) * rn);
                    }
                } else {
                    int rt = rtb + r;
                    bool ok = (row < n);
                    #pragma unroll
                    for (int nt = 0; nt < 8; ++nt) {
                        int kd = nt * 16 + l15;
                        float on = (acc[nt][r] + bb[nt]) * rn;
                        unsigned short v16 = ok ? f2bf(on) : (unsigned short)0;
                        int byte = kd * 128 + ((2 * rt) ^ ((kd & 7) << 4));
                        *(unsigned short*)(cA + byte) = v16;
                        sk8[nt] += ok ? on : 0.f;
                    }
                }
            }
            if (m == 1) {
                #pragma unroll
                for (int nt = 0; nt < 8; ++nt) {
                    float s = sk8[nt];
                    s += __shfl_xor(s, 16);
                    s += __shfl_xor(s, 32);
                    skred[nt] = s;          // valid in lanes < 16
                }
            }
        } else if (m == 2) {                // v -> vT LDS tile + reg sum
            float sv8[8] = {};
            #pragma unroll
            for (int r = 0; r < 4; ++r) {
                int row = rbase + r;
                int rt = rtb + r;
                bool ok = (row < n);
                #pragma unroll
                for (int nt = 0; nt < 8; ++nt) {
                    int vd = nt * 16 + l15;
                    float on = acc[nt][r] + bb[nt];
                    unsigned short v16 = ok ? f2bf(on) : (unsigned short)0;
                    int byte = vd * 128 + ((2 * rt) ^ ((vd & 7) << 4));
                    *(unsigned short*)(cVT + byte) = v16;
                    sv8[nt] += ok ? on : 0.f;
                }
            }
            #pragma unroll
            for (int nt = 0; nt < 8; ++nt) {
                float s = sv8[nt];
                s += __shfl_xor(s, 16);
                s += __shfl_xor(s, 32);
                svred[nt] = s;              // valid in lanes < 16
            }
        } else if (m == 3) {                // g: bias, fp8 store
            #pragma unroll
            for (int r = 0; r < 4; ++r) {
                int row = rbase + r;
                if (row < n) {
                    #pragma unroll
                    for (int nt = 0; nt < 8; ++nt)
                        gb8[(size_t)row * HID + nt * 16 + l15] = f2fp8(acc[nt][r] + bb[nt]);
                }
            }
        } else {                            // r: bias + residual(h)
            #pragma unroll
            for (int r = 0; r < 4; ++r) {
                int row = rbase + r;
                if (row < n) {
                    #pragma unroll
                    for (int nt = 0; nt < 8; ++nt) {
                        int col = nt * 16 + l15;
                        accout[(size_t)row * HID + col] =
                            acc[nt][r] + bb[nt] + bf2f(A16[(size_t)row * HID + col]);
                    }
                }
            }
        }
        // no barrier: knT/vT have no cross-wave readers until the tail
    }
    __syncthreads();                        // knT/vT writes visible to all

    // ---- tail: partial kvs[kd][vd] = sum_r knT[kd][r] * vT[vd][r], K=64 ----
    f32x4 kacc[2][8] = {};
    #pragma unroll
    for (int ks = 0; ks < 2; ++ks) {
        #pragma unroll
        for (int mt = 0; mt < 2; ++mt) {
            int kd = w * 32 + mt * 16 + l15;
            int aoff = kd * 128 + ((ks * 64 + (l >> 4) * 16) ^ ((kd & 7) << 4));
            s16x8 fa = *(s16x8*)(cA + aoff);
            #pragma unroll
            for (int nt = 0; nt < 8; ++nt) {
                int vd = nt * 16 + l15;
                int boff = vd * 128 + ((ks * 64 + (l >> 4) * 16) ^ ((vd & 7) << 4));
                kacc[mt][nt] = __builtin_amdgcn_mfma_f32_16x16x32_bf16(fa, *(s16x8*)(cVT + boff), kacc[mt][nt], 0, 0, 0);
            }
        }
    }
    __syncthreads();                        // all tail reads of cA done

    // ---- stash wave sums in the now-dead cA region ----
    float* sksf = (float*)cA;               // [4][128]
    float* svsf = (float*)(cA + 2048);      // [4][128]
    if (l < 16) {
        #pragma unroll
        for (int nt = 0; nt < 8; ++nt) {
            sksf[w * 128 + nt * 16 + l15] = skred[nt];
            svsf[w * 128 + nt * 16 + l15] = svred[nt];
        }
    }
    __syncthreads();

    unsigned short* pb = partial + (size_t)blockIdx.x * 16640;
    #pragma unroll
    for (int mt = 0; mt < 2; ++mt) {
        #pragma unroll
        for (int nt = 0; nt < 8; ++nt) {
            #pragma unroll
            for (int r = 0; r < 4; ++r) {
                int kd = w * 32 + mt * 16 + ((l >> 4) << 2) + r;
                pb[kd * 128 + nt * 16 + l15] = f2bf(kacc[mt][nt][r]);
            }
        }
    }
    if (t < 128) {
        pb[16384 + t] = f2bf(sksf[t] + sksf[128 + t] + sksf[256 + t] + sksf[384 + t]);
    } else {
        int vd = t - 128;
        pb[16512 + vd] = f2bf(svsf[vd] + svsf[128 + vd] + svsf[256 + vd] + svsf[384 + vd]);
    }
}

// ---------------------------------------------------------------------------
// num+combine (R16 structure): accio += (qn @ kvs + sum_v) / (qn.sum_kn + nf)
// ---------------------------------------------------------------------------
__global__ __launch_bounds__(256) void gemm_num_combine(
    const unsigned short* __restrict__ A16,
    const unsigned short* __restrict__ Bth,
    const float* __restrict__ sumv, const float* __restrict__ snk,
    float nf, float* __restrict__ accio, int n,
    const int* __restrict__ ei, int* cntp, int* crowp, int Etot, int e0, int e1,
    int hostGrid)
{
    if (csr_side(hostGrid, ei, cntp, crowp, Etot, e0, e1)) return;

    __shared__ char smem2[16384 + 32768];
    char* cA = smem2;
    char* cW = smem2 + 16384;

    const int t = threadIdx.x;
    const int l = t & 63;
    const int w = t >> 6;
    const int l15 = l & 15;
    const int row0 = blockIdx.x * 64;

    #pragma unroll
    for (int i = 0; i < 4; ++i) {
        int f = t + 256 * i;
        int r = f >> 4, c8 = f & 15;
        int gr = row0 + r; if (gr > n - 1) gr = n - 1;
        int byte = r * 256 + ((c8 * 16) ^ ((r & 7) << 4));
        *(s16x8*)(cA + byte) = *(const s16x8*)&A16[(size_t)gr * HID + c8 * 8];
    }
    #pragma unroll
    for (int i = 0; i < 8; ++i) {
        int f = t + 256 * i;
        int nr = f >> 4, c8 = f & 15;
        int byte = nr * 256 + ((c8 * 16) ^ ((nr & 7) << 4));
        *(s16x8*)(cW + byte) = *(const s16x8*)&Bth[(size_t)nr * HID + c8 * 8];
    }
    __syncthreads();

    f32x4 acc[8] = {};
    const int arow = w * 16 + l15;
    #pragma unroll
    for (int ks = 0; ks < 4; ++ks) {
        int aoff = arow * 256 + (((ks * 64) + (l >> 4) * 16) ^ ((arow & 7) << 4));
        s16x8 fa = *(s16x8*)(cA + aoff);
        #pragma unroll
        for (int nt = 0; nt < 8; ++nt) {
            int nr = nt * 16 + l15;
            int boff = nr * 256 + (((ks * 64) + (l >> 4) * 16) ^ ((nr & 7) << 4));
            acc[nt] = __builtin_amdgcn_mfma_f32_16x16x32_bf16(fa, *(s16x8*)(cW + boff), acc[nt], 0, 0, 0);
        }
    }

    const int rbase = row0 + w * 16 + ((l >> 4) << 2);
    const int rtb   = w * 16 + ((l >> 4) << 2);
    float bb[8], skn[8];
    #pragma unroll
    for (int nt = 0; nt < 8; ++nt) {
        bb[nt]  = sumv[nt * 16 + l15];
        skn[nt] = snk[nt * 16 + l15];
    }
    #pragma unroll
    for (int r = 0; r < 4; ++r) {
        int row = rbase + r;
        int rt = rtb + r;
        float p = 0.f;
        #pragma unroll
        for (int nt = 0; nt < 8; ++nt) {
            int byte = rt * 256 + ((2 * (nt * 16 + l15)) ^ ((rt & 7) << 4));
            p += bf2f(*(unsigned short*)(cA + byte)) * skn[nt];
        }
        p += __shfl_xor(p, 1); p += __shfl_xor(p, 2);
        p += __shfl_xor(p, 4); p += __shfl_xor(p, 8);
        float dinv = 1.f / (p + nf);
        if (row < n) {
            #pragma unroll
            for (int nt = 0; nt < 8; ++nt) {
                size_t idx = (size_t)row * HID + nt * 16 + l15;
                accio[idx] += (acc[nt][r] + bb[nt]) * dinv;
            }
        }
    }
}

// ------------------- weight pre-convert (+transpose), hi-only ---------------
struct WConvArgs {
    const float* src[18];
    unsigned short* dh[18];
    int K[18];
};

__global__ void conv_weights(WConvArgs a)
{
    int m = blockIdx.x;
    const float* s = a.src[m];
    unsigned short* dh = a.dh[m];
    int K = a.K[m];
    int tot = 128 * K;
    int slice = (tot + gridDim.y - 1) / gridDim.y;
    int i0 = blockIdx.y * slice;
    int i1 = min(tot, i0 + slice);
    for (int idx = i0 + threadIdx.x; idx < i1; idx += 256) {
        int nn = idx / K, k = idx - nn * K;
        dh[idx] = f2bf(s[(size_t)k * 128 + nn]);
    }
}

// ---- kvs reduce stage A: grid (17, P2G); thread owns an output-quad --------
__global__ __launch_bounds__(256) void reduce_kvs_p2a(
    const unsigned short* __restrict__ partial, int nb,
    float* __restrict__ partial2)
{
    const int oq = blockIdx.x * 256 + threadIdx.x;      // output quad 0..4159
    if (oq >= 4160) return;
    const int g   = blockIdx.y;
    const int per = (nb + P2G - 1) / P2G;
    const int b0  = g * per;
    const int b1  = min(nb, b0 + per);

    float s0 = 0.f, s1 = 0.f, s2 = 0.f, s3 = 0.f;
    int b = b0;
    for (; b + 3 < b1; b += 4) {
        us16x4 u0 = *(const us16x4*)&partial[(size_t)(b + 0) * 16640 + oq * 4];
        us16x4 u1 = *(const us16x4*)&partial[(size_t)(b + 1) * 16640 + oq * 4];
        us16x4 u2 = *(const us16x4*)&partial[(size_t)(b + 2) * 16640 + oq * 4];
        us16x4 u3 = *(const us16x4*)&partial[(size_t)(b + 3) * 16640 + oq * 4];
        s0 += bf2f(u0[0]) + bf2f(u1[0]) + bf2f(u2[0]) + bf2f(u3[0]);
        s1 += bf2f(u0[1]) + bf2f(u1[1]) + bf2f(u2[1]) + bf2f(u3[1]);
        s2 += bf2f(u0[2]) + bf2f(u1[2]) + bf2f(u2[2]) + bf2f(u3[2]);
        s3 += bf2f(u0[3]) + bf2f(u1[3]) + bf2f(u2[3]) + bf2f(u3[3]);
    }
    for (; b < b1; ++b) {
        us16x4 u0 = *(const us16x4*)&partial[(size_t)b * 16640 + oq * 4];
        s0 += bf2f(u0[0]); s1 += bf2f(u0[1]); s2 += bf2f(u0[2]); s3 += bf2f(u0[3]);
    }
    *(f32x4*)&partial2[(size_t)g * 16640 + oq * 4] = (f32x4){s0, s1, s2, s3};
}

// ---- kvs reduce stage B: 65 blocks; sum P2G groups -> kvth + sums ----------
__global__ __launch_bounds__(256) void reduce_kvs_p2b(
    const float* __restrict__ partial2,
    unsigned short* __restrict__ kvth, float* __restrict__ sums)
{
    int o = blockIdx.x * 256 + threadIdx.x;
    if (o >= 16640) return;
    float tot = 0.f;
    #pragma unroll
    for (int g = 0; g < P2G; ++g)
        tot += partial2[(size_t)g * 16640 + o];
    if (o < 16384) {
        int k = o >> 7, nn = o & 127;
        kvth[nn * 128 + k] = f2bf(tot);
    } else {
        sums[o - 16384] = tot;
    }
}

__global__ void rdeg_k(const int* __restrict__ cur, float* __restrict__ rdeg, int n)
{
    int i = blockIdx.x * 256 + threadIdx.x;
    if (i < n) {
        int c = cur[i];
        rdeg[i] = (c > 0) ? rsqrtf((float)c) : 0.f;
    }
}

// ------ fused gather + LN + ELU: 4 nodes/wave (16 lanes/node), 8B loads -----
__global__ __launch_bounds__(256) void gather_ln_elu4(
    const int* __restrict__ cnt, const int* __restrict__ crow,
    const float* __restrict__ rdeg,
    const unsigned char* __restrict__ g, const float* __restrict__ accin,
    const float* __restrict__ gam, const float* __restrict__ bet,
    float* __restrict__ outf, unsigned short* __restrict__ out16, int n)
{
    int node = (int)((blockIdx.x * 256 + threadIdx.x) >> 4);
    int li   = threadIdx.x & 15;
    if (node >= n) return;

    int cn = cnt[node]; if (cn > SLOTS) cn = SLOTS;
    const int* cr = &crow[(size_t)node * SLOTS];
    float rd = rdeg[node];
    const unsigned b8 = (unsigned)li * 8u;
    float4 a0 = *(const float4*)&accin[(size_t)node * HID + li * 8];
    float4 a1 = *(const float4*)&accin[(size_t)node * HID + li * 8 + 4];

    auto acc8 = [&](uint2 U_, float W_) {
        f32x2 pa = __builtin_amdgcn_cvt_pk_f32_fp8((int)U_.x, false);
        f32x2 pb = __builtin_amdgcn_cvt_pk_f32_fp8((int)U_.x, true);
        f32x2 pc = __builtin_amdgcn_cvt_pk_f32_fp8((int)U_.y, false);
        f32x2 pd = __builtin_amdgcn_cvt_pk_f32_fp8((int)U_.y, true);
        a0.x += W_ * pa[0]; a0.y += W_ * pa[1];
        a0.z += W_ * pb[0]; a0.w += W_ * pb[1];
        a1.x += W_ * pc[0]; a1.y += W_ * pc[1];
        a1.z += W_ * pd[0]; a1.w += W_ * pd[1];
    };

    int i = 0;
    for (; i + 3 < cn; i += 4) {
        int   r0 = cr[i],     r1 = cr[i + 1];
        int   r2 = cr[i + 2], r3 = cr[i + 3];
        float w0 = rd * rdeg[r0], w1 = rd * rdeg[r1];
        float w2 = rd * rdeg[r2], w3 = rd * rdeg[r3];
        uint2 u0 = *(const uint2*)&g[(unsigned)r0 * 128u + b8];
        uint2 u1 = *(const uint2*)&g[(unsigned)r1 * 128u + b8];
        uint2 u2 = *(const uint2*)&g[(unsigned)r2 * 128u + b8];
        uint2 u3 = *(const uint2*)&g[(unsigned)r3 * 128u + b8];
        acc8(u0, w0); acc8(u1, w1); acc8(u2, w2); acc8(u3, w3);
    }
    for (; i < cn; ++i) {
        int r0 = cr[i];
        float w0 = rd * rdeg[r0];
        uint2 u0 = *(const uint2*)&g[(unsigned)r0 * 128u + b8];
        acc8(u0, w0);
    }

    float sm = a0.x + a0.y + a0.z + a0.w + a1.x + a1.y + a1.z + a1.w;
    float ss = a0.x * a0.x + a0.y * a0.y + a0.z * a0.z + a0.w * a0.w
             + a1.x * a1.x + a1.y * a1.y + a1.z * a1.z + a1.w * a1.w;
    #pragma unroll
    for (int o = 8; o; o >>= 1) { sm += __shfl_xor(sm, o); ss += __shfl_xor(ss, o); }
    float mu  = sm * (1.f / 128.f);
    float var = ss * (1.f / 128.f) - mu * mu;
    float rs  = rsqrtf(var + EPS);
    float4 gm0 = *(const float4*)&gam[li * 8];
    float4 gm1 = *(const float4*)&gam[li * 8 + 4];
    float4 bt0 = *(const float4*)&bet[li * 8];
    float4 bt1 = *(const float4*)&bet[li * 8 + 4];
    float y0 = eluf((a0.x - mu) * rs * gm0.x + bt0.x);
    float y1 = eluf((a0.y - mu) * rs * gm0.y + bt0.y);
    float y2 = eluf((a0.z - mu) * rs * gm0.z + bt0.z);
    float y3 = eluf((a0.w - mu) * rs * gm0.w + bt0.w);
    float y4 = eluf((a1.x - mu) * rs * gm1.x + bt1.x);
    float y5 = eluf((a1.y - mu) * rs * gm1.y + bt1.y);
    float y6 = eluf((a1.z - mu) * rs * gm1.z + bt1.z);
    float y7 = eluf((a1.w - mu) * rs * gm1.w + bt1.w);
    if (out16) {
        us16x4 o0 = (us16x4){f2bf(y0), f2bf(y1), f2bf(y2), f2bf(y3)};
        us16x4 o1 = (us16x4){f2bf(y4), f2bf(y5), f2bf(y6), f2bf(y7)};
        *(us16x4*)&out16[(size_t)node * HID + li * 8]     = o0;
        *(us16x4*)&out16[(size_t)node * HID + li * 8 + 4] = o1;
    } else {
        *(float4*)&outf[(size_t)node * HID + li * 8]     = make_float4(y0, y1, y2, y3);
        *(float4*)&outf[(size_t)node * HID + li * 8 + 4] = make_float4(y4, y5, y6, y7);
    }
}

// ---------------------------------------------------------------------------
extern "C" void kernel_launch(void* const* d_in, const int* in_sizes, int n_in,
                              void* d_out, int out_size, void* d_ws, size_t ws_size,
                              hipStream_t stream)
{
    const float* x      = (const float*)d_in[0];
    const int*   ei     = (const int*)  d_in[1];
    const float* mlp_W0 = (const float*)d_in[2];
    const float* mlp_b0 = (const float*)d_in[3];
    const float* mlp_W  = (const float*)d_in[4];
    const float* mlp_b  = (const float*)d_in[5];
    const float* bn_g   = (const float*)d_in[6];
    const float* bn_b   = (const float*)d_in[7];
    const float* bn_m   = (const float*)d_in[8];
    const float* bn_v   = (const float*)d_in[9];
    const float* Wq = (const float*)d_in[10]; const float* bq = (const float*)d_in[11];
    const float* Wk = (const float*)d_in[12]; const float* bk = (const float*)d_in[13];
    const float* Wv = (const float*)d_in[14]; const float* bv = (const float*)d_in[15];
    const float* Wg = (const float*)d_in[16]; const float* bg = (const float*)d_in[17];
    const float* Wr = (const float*)d_in[18]; const float* br = (const float*)d_in[19];
    const float* ln_g = (const float*)d_in[20];
    const float* ln_b = (const float*)d_in[21];

    const int N = in_sizes[0] / INC;
    const int E = in_sizes[1] / 2;
    const size_t P = (size_t)N * HID;
    const int gemmGrid = (N + 63) / 64;

    // workspace layout
    unsigned short* partial = (unsigned short*)d_ws;            // max(gemmGrid*16640, P) bf16
    size_t partUS = (size_t)gemmGrid * 16640;
    if (partUS < P) partUS = P;
    unsigned short* h16  = partial + partUS;                    // P bf16
    unsigned short* qb16 = h16 + P;                             // P bf16
    unsigned char*  gb8  = (unsigned char*)(qb16 + P);          // P fp8
    float* kvs  = (float*)(gb8 + P);                            // 256 f
    float* partial2 = kvs + 256;                                // P2G*16640 f32
    int*   crow = (int*)(partial2 + (size_t)P2G * 16640);       // N*SLOTS
    int*   cnt  = crow + (size_t)N * SLOTS;                     // N
    float* rdeg = (float*)(cnt + N);                            // N
    unsigned short* wt = (unsigned short*)(rdeg + N);

    // MLP scratch (dead before first partial/qb16 use)
    unsigned short* mlpA = partial;
    unsigned short* mlpB = qb16;

    unsigned short* WTh[18];
    int Ks[18];
    size_t woff = 0;
    for (int m = 0; m < 18; ++m) {
        int K = (m == 0) ? INC : HID;
        Ks[m] = K;
        WTh[m] = wt + woff;           woff += (size_t)128 * K;
    }
    unsigned short* kvth = wt + woff; woff += 16384;
    float* acc = (float*)d_out;

    const int gw4Grid  = (N + 15) / 16;
    const int nodeGrid = (N + 255) / 256;

    // CSR chunk bounds: 5 chunks hidden under MLP0/1/2, qkvgr0, num_combine0
    int eb[6];
    for (int i = 0; i <= 5; ++i) eb[i] = (int)(((long long)E * i) / 5);
    auto cb = [&](int i) { return (eb[i + 1] - eb[i] + 255) / 256; };

    // --- weight pre-convert (hi-only, transposed) ---
    WConvArgs wa;
    const float* srcs[18];
    srcs[0] = mlp_W0; srcs[1] = mlp_W; srcs[2] = mlp_W + (size_t)HID * HID;
    for (int l = 0; l < NLAYER; ++l) {
        const size_t wo = (size_t)l * HID * HID;
        srcs[3 + l * 5 + 0] = Wq + wo;
        srcs[3 + l * 5 + 1] = Wk + wo;
        srcs[3 + l * 5 + 2] = Wv + wo;
        srcs[3 + l * 5 + 3] = Wg + wo;
        srcs[3 + l * 5 + 4] = Wr + wo;
    }
    for (int m = 0; m < 18; ++m) {
        wa.src[m] = srcs[m]; wa.dh[m] = WTh[m]; wa.K[m] = Ks[m];
    }
    conv_weights<<<dim3(18, 8), 256, 0, stream>>>(wa);

    hipMemsetAsync(cnt, 0, (size_t)N * sizeof(int), stream);

    // --- MLP (each hosts a CSR chunk) ---
    gemm_mlp<INC, true><<<gemmGrid + cb(0), 256, 0, stream>>>(x, nullptr, WTh[0], mlp_b0,
        bn_g, bn_b, bn_m, bn_v, mlpA, N, ei, cnt, crow, E, eb[0], eb[1], gemmGrid);
    gemm_mlp<HID, false><<<gemmGrid + cb(1), 256, 0, stream>>>(nullptr, mlpA, WTh[1], mlp_b,
        bn_g + HID, bn_b + HID, bn_m + HID, bn_v + HID, mlpB, N,
        ei, cnt, crow, E, eb[1], eb[2], gemmGrid);
    gemm_mlp<HID, false><<<gemmGrid + cb(2), 256, 0, stream>>>(nullptr, mlpB, WTh[2], mlp_b + HID,
        bn_g + 2 * HID, bn_b + 2 * HID, bn_m + 2 * HID, bn_v + 2 * HID, h16, N,
        ei, cnt, crow, E, eb[2], eb[3], gemmGrid);

    // --- TransConv layers ---
    for (int l = 0; l < NLAYER; ++l) {
        const int bo = l * HID;
        const bool l0 = (l == 0);

        QKVGRArgs qa;
        for (int m = 0; m < 5; ++m) qa.wh[m] = WTh[3 + l * 5 + m];
        qa.bias[0] = bq + bo; qa.bias[1] = bk + bo; qa.bias[2] = bv + bo;
        qa.bias[3] = bg + bo; qa.bias[4] = br + bo;

        // h16 -> qn, g, acc(r+res), partial kvs  (layer 0 hosts CSR chunk 3)
        fused_qkvgr<<<gemmGrid + (l0 ? cb(3) : 0), 256, 0, stream>>>(h16, qa,
            qb16, gb8, acc, partial, N,
            ei, cnt, crow, E, l0 ? eb[3] : 0, l0 ? eb[4] : 0, gemmGrid);

        // kvs = sum of per-block partials (two-stage, parallel)
        reduce_kvs_p2a<<<dim3(17, P2G), 256, 0, stream>>>(partial, gemmGrid, partial2);
        reduce_kvs_p2b<<<65, 256, 0, stream>>>(partial2, kvth, kvs);

        // acc += (qn @ kvs + sum_v) / (qn . sum_kn + N)  (layer 0 hosts chunk 4)
        gemm_num_combine<<<gemmGrid + (l0 ? cb(4) : 0), 256, 0, stream>>>(qb16, kvth,
            kvs + 128, kvs, (float)N, acc, N,
            ei, cnt, crow, E, l0 ? eb[4] : 0, l0 ? eb[5] : 0, gemmGrid);

        // rdeg after the last CSR chunk, before the first gather
        if (l0) rdeg_k<<<nodeGrid, 256, 0, stream>>>(cnt, rdeg, N);

        // fused gather (fp8 g, 4 nodes/wave) + LN + ELU
        bool last = (l == NLAYER - 1);
        gather_ln_elu4<<<gw4Grid, 256, 0, stream>>>(cnt, crow, rdeg,
            gb8, acc, ln_g + bo, ln_b + bo,
            last ? acc : nullptr, last ? nullptr : h16, N);
    }
}

// Round 20
// 764.955 us; speedup vs baseline: 1.3423x; 1.3423x over previous
//
#include <hip/hip_runtime.h>
#include <cstdint>
#include <cstddef>

#define HID 128
#define INC 256
#define NLAYER 3
#define SLOTS 96
#define P2G 16            // partial-reduction groups

static constexpr float EPS = 1e-5f;

typedef __attribute__((ext_vector_type(8))) short s16x8;
typedef __attribute__((ext_vector_type(4))) unsigned short us16x4;
typedef __attribute__((ext_vector_type(4))) float f32x4;
typedef __attribute__((ext_vector_type(2))) float f32x2;

__device__ __forceinline__ float eluf(float x) { return x > 0.f ? x : expm1f(x); }

__device__ __forceinline__ unsigned short f2bf(float x)
{
    unsigned u = __float_as_uint(x);
    u += 0x7FFFu + ((u >> 16) & 1u);
    return (unsigned short)(u >> 16);
}

__device__ __forceinline__ float bf2f(unsigned short u)
{
    return __uint_as_float(((unsigned)u) << 16);
}

__device__ __forceinline__ unsigned char f2fp8(float x)
{
    return (unsigned char)(__builtin_amdgcn_cvt_pk_fp8_f32(x, x, 0, false) & 0xFF);
}

// ---- CSR co-run side-job: blocks past hostGrid fill an edge range ----------
__device__ __forceinline__ bool csr_side(int hostGrid, const int* __restrict__ ei,
                                         int* cnt, int* crow, int Etot, int e0, int e1)
{
    if ((int)blockIdx.x < hostGrid) return false;
    int e = e0 + (int)(blockIdx.x - hostGrid) * 256 + (int)threadIdx.x;
    if (e < e1) {
        int r = ei[e], c = ei[Etot + e];
        int p = atomicAdd(&cnt[c], 1);
        if (p < SLOTS) crow[(size_t)c * SLOTS + p] = r;
    }
    return true;
}

// ---------------------------------------------------------------------------
// MLP GEMM, hi-only bf16: C16 = bf16(ELU(BN(A[n,K] @ W + bias))).
// ---------------------------------------------------------------------------
template<int K, bool IN32>
__global__ __launch_bounds__(256) void gemm_mlp(
    const float* __restrict__ Af, const unsigned short* __restrict__ A16,
    const unsigned short* __restrict__ Wth,
    const float* __restrict__ bias,
    const float* __restrict__ bng, const float* __restrict__ bnb,
    const float* __restrict__ bnm, const float* __restrict__ bnv,
    unsigned short* __restrict__ C16, int n,
    const int* __restrict__ ei, int* cntp, int* crowp, int Etot, int e0, int e1,
    int hostGrid)
{
    if (csr_side(hostGrid, ei, cntp, crowp, Etot, e0, e1)) return;

    __shared__ unsigned short Ah[64 * 64], Wh[128 * 64];
    const int t = threadIdx.x;
    const int l = t & 63;
    const int w = t >> 6;
    const int l15 = l & 15;
    const int row0 = blockIdx.x * 64;

    char* cAh = (char*)Ah;
    char* cWh = (char*)Wh;

    f32x4 acc[8] = {};

    for (int kc = 0; kc < K; kc += 64) {
        if (IN32) {
            #pragma unroll
            for (int i = 0; i < 4; ++i) {
                int f = t + 256 * i;
                int r = f >> 4, c4 = f & 15;
                int gr = row0 + r; if (gr > n - 1) gr = n - 1;
                float4 a4 = *(const float4*)&Af[(size_t)gr * K + kc + c4 * 4];
                int byte = r * 128 + (((c4 >> 1) * 16) ^ ((r & 7) << 4)) + (c4 & 1) * 8;
                *(us16x4*)(cAh + byte) =
                    (us16x4){f2bf(a4.x), f2bf(a4.y), f2bf(a4.z), f2bf(a4.w)};
            }
        } else {
            #pragma unroll
            for (int i = 0; i < 2; ++i) {
                int f = t + 256 * i;
                int r = f >> 3, c8 = f & 7;
                int gr = row0 + r; if (gr > n - 1) gr = n - 1;
                int byte = r * 128 + ((c8 * 16) ^ ((r & 7) << 4));
                *(s16x8*)(cAh + byte) = *(const s16x8*)&A16[(size_t)gr * K + kc + c8 * 8];
            }
        }
        #pragma unroll
        for (int i = 0; i < 4; ++i) {
            int f = t + 256 * i;
            int nr = f >> 3, c8 = f & 7;
            size_t gsrc = (size_t)nr * K + kc + c8 * 8;
            int byte = nr * 128 + ((c8 * 16) ^ ((nr & 7) << 4));
            *(s16x8*)(cWh + byte) = *(const s16x8*)&Wth[gsrc];
        }
        __syncthreads();
        #pragma unroll
        for (int ks = 0; ks < 2; ++ks) {
            int jA = ks * 4 + (l >> 4);
            int ar = w * 16 + l15;
            int aoff = ar * 128 + ((jA * 16) ^ ((ar & 7) << 4));
            s16x8 fah = *(s16x8*)(cAh + aoff);
            #pragma unroll
            for (int nt = 0; nt < 8; ++nt) {
                int nr = nt * 16 + l15;
                int boff = nr * 128 + ((jA * 16) ^ ((nr & 7) << 4));
                acc[nt] = __builtin_amdgcn_mfma_f32_16x16x32_bf16(fah, *(s16x8*)(cWh + boff), acc[nt], 0, 0, 0);
            }
        }
        __syncthreads();
    }

    const int rbase = row0 + w * 16 + ((l >> 4) << 2);
    #pragma unroll
    for (int nt = 0; nt < 8; ++nt) {
        int col = nt * 16 + l15;
        float bb = bias[col];
        float gm = bng[col], bt = bnb[col], mn = bnm[col], vr = bnv[col];
        #pragma unroll
        for (int r = 0; r < 4; ++r) {
            int row = rbase + r;
            if (row < n) {
                float o = acc[nt][r] + bb;
                o = eluf((o - mn) * rsqrtf(vr + EPS) * gm + bt);
                C16[(size_t)row * HID + col] = f2bf(o);
            }
        }
    }
}

// ---------------------------------------------------------------------------
// Fused per-layer QKVGR + kvs: hi-only bf16, W staged per-matrix (R16 best).
// LDS exactly 64KB -> 2 blocks/CU. Reg-held sums, stashed in dead cW.
// ---------------------------------------------------------------------------
struct QKVGRArgs {
    const unsigned short* wh[5];
    const float* bias[5];
};

__global__ __launch_bounds__(256) void fused_qkvgr(
    const unsigned short* __restrict__ A16, QKVGRArgs ar,
    unsigned short* __restrict__ qb16,
    unsigned char* __restrict__ gb8, float* __restrict__ accout,
    unsigned short* __restrict__ partial, int n,
    const int* __restrict__ ei, int* cntp, int* crowp, int Etot, int e0, int e1,
    int hostGrid)
{
    if (csr_side(hostGrid, ei, cntp, crowp, Etot, e0, e1)) return;

    __shared__ char smem[65536];
    char* cA  = smem;             // 16KB: staged h; becomes knT after m=1
    char* cW  = smem + 16384;     // 32KB: W; sum stash after the loop
    char* cVT = smem + 49152;     // 16KB: vT

    const int t = threadIdx.x;
    const int l = t & 63;
    const int w = t >> 6;
    const int l15 = l & 15;
    const int row0 = blockIdx.x * 64;

    // ---- stage A (bf16, swizzled, row stride 256B) ----
    #pragma unroll
    for (int i = 0; i < 4; ++i) {
        int f = t + 256 * i;
        int r = f >> 4, c8 = f & 15;
        int gr = row0 + r; if (gr > n - 1) gr = n - 1;
        int byte = r * 256 + ((c8 * 16) ^ ((r & 7) << 4));
        *(s16x8*)(cA + byte) = *(const s16x8*)&A16[(size_t)gr * HID + c8 * 8];
    }
    __syncthreads();

    s16x8 fah[4];
    {
        const int arow = w * 16 + l15;
        #pragma unroll
        for (int ks = 0; ks < 4; ++ks) {
            int aoff = arow * 256 + (((ks * 64) + (l >> 4) * 16) ^ ((arow & 7) << 4));
            fah[ks] = *(s16x8*)(cA + aoff);
        }
    }
    __syncthreads();   // all frags loaded before cA is reused at m=1

    const int rbase = row0 + w * 16 + ((l >> 4) << 2);
    const int rtb   = w * 16 + ((l >> 4) << 2);
    float skred[8], svred[8];

    for (int m = 0; m < 5; ++m) {
        // ---- stage Wm ----
        {
            const unsigned short* wh = ar.wh[m];
            #pragma unroll
            for (int i = 0; i < 8; ++i) {
                int f = t + 256 * i;
                int nr = f >> 4, c8 = f & 15;
                int byte = nr * 256 + ((c8 * 16) ^ ((nr & 7) << 4));
                *(s16x8*)(cW + byte) = *(const s16x8*)&wh[(size_t)nr * HID + c8 * 8];
            }
        }
        __syncthreads();

        f32x4 acc[8] = {};
        #pragma unroll
        for (int ks = 0; ks < 4; ++ks) {
            #pragma unroll
            for (int nt = 0; nt < 8; ++nt) {
                int nr = nt * 16 + l15;
                int boff = nr * 256 + (((ks * 64) + (l >> 4) * 16) ^ ((nr & 7) << 4));
                acc[nt] = __builtin_amdgcn_mfma_f32_16x16x32_bf16(fah[ks], *(s16x8*)(cW + boff), acc[nt], 0, 0, 0);
            }
        }

        float bb[8];
        #pragma unroll
        for (int nt = 0; nt < 8; ++nt) bb[nt] = ar.bias[m][nt * 16 + l15];

        if (m <= 1) {                       // q / k: bias + row L2 normalize
            float sk8[8] = {};
            #pragma unroll
            for (int r = 0; r < 4; ++r) {
                float ss = 0.f;
                #pragma unroll
                for (int nt = 0; nt < 8; ++nt) {
                    float o = acc[nt][r] + bb[nt];
                    ss += o * o;
                }
                ss += __shfl_xor(ss, 1); ss += __shfl_xor(ss, 2);
                ss += __shfl_xor(ss, 4); ss += __shfl_xor(ss, 8);
                float rn = rsqrtf(ss);
                int row = rbase + r;
                if (m == 0) {
                    if (row < n) {
                        #pragma unroll
                        for (int nt = 0; nt < 8; ++nt)
                            qb16[(size_t)row * HID + nt * 16 + l15] = f2bf((acc[nt][r] + bb[nt]) * rn);
                    }
                } else {
                    int rt = rtb + r;
                    bool ok = (row < n);
                    #pragma unroll
                    for (int nt = 0; nt < 8; ++nt) {
                        int kd = nt * 16 + l15;
                        float on = (acc[nt][r] + bb[nt]) * rn;
                        unsigned short v16 = ok ? f2bf(on) : (unsigned short)0;
                        int byte = kd * 128 + ((2 * rt) ^ ((kd & 7) << 4));
                        *(unsigned short*)(cA + byte) = v16;
                        sk8[nt] += ok ? on : 0.f;
                    }
                }
            }
            if (m == 1) {
                #pragma unroll
                for (int nt = 0; nt < 8; ++nt) {
                    float s = sk8[nt];
                    s += __shfl_xor(s, 16);
                    s += __shfl_xor(s, 32);
                    skred[nt] = s;          // valid in lanes < 16
                }
            }
        } else if (m == 2) {                // v -> vT LDS tile + reg sum
            float sv8[8] = {};
            #pragma unroll
            for (int r = 0; r < 4; ++r) {
                int row = rbase + r;
                int rt = rtb + r;
                bool ok = (row < n);
                #pragma unroll
                for (int nt = 0; nt < 8; ++nt) {
                    int vd = nt * 16 + l15;
                    float on = acc[nt][r] + bb[nt];
                    unsigned short v16 = ok ? f2bf(on) : (unsigned short)0;
                    int byte = vd * 128 + ((2 * rt) ^ ((vd & 7) << 4));
                    *(unsigned short*)(cVT + byte) = v16;
                    sv8[nt] += ok ? on : 0.f;
                }
            }
            #pragma unroll
            for (int nt = 0; nt < 8; ++nt) {
                float s = sv8[nt];
                s += __shfl_xor(s, 16);
                s += __shfl_xor(s, 32);
                svred[nt] = s;              // valid in lanes < 16
            }
        } else if (m == 3) {                // g: bias, fp8 store
            #pragma unroll
            for (int r = 0; r < 4; ++r) {
                int row = rbase + r;
                if (row < n) {
                    #pragma unroll
                    for (int nt = 0; nt < 8; ++nt)
                        gb8[(size_t)row * HID + nt * 16 + l15] = f2fp8(acc[nt][r] + bb[nt]);
                }
            }
        } else {                            // r: bias + residual(h)
            #pragma unroll
            for (int r = 0; r < 4; ++r) {
                int row = rbase + r;
                if (row < n) {
                    #pragma unroll
                    for (int nt = 0; nt < 8; ++nt) {
                        int col = nt * 16 + l15;
                        accout[(size_t)row * HID + col] =
                            acc[nt][r] + bb[nt] + bf2f(A16[(size_t)row * HID + col]);
                    }
                }
            }
        }
        __syncthreads();
    }

    // ---- stash wave sums in the dead cW region ----
    float* sksf = (float*)cW;               // [4][128]
    float* svsf = (float*)(cW + 2048);      // [4][128]
    if (l < 16) {
        #pragma unroll
        for (int nt = 0; nt < 8; ++nt) {
            sksf[w * 128 + nt * 16 + l15] = skred[nt];
            svsf[w * 128 + nt * 16 + l15] = svred[nt];
        }
    }

    // ---- tail: partial kvs[kd][vd] = sum_r knT[kd][r] * vT[vd][r], K=64 ----
    f32x4 kacc[2][8] = {};
    #pragma unroll
    for (int ks = 0; ks < 2; ++ks) {
        #pragma unroll
        for (int mt = 0; mt < 2; ++mt) {
            int kd = w * 32 + mt * 16 + l15;
            int aoff = kd * 128 + ((ks * 64 + (l >> 4) * 16) ^ ((kd & 7) << 4));
            s16x8 fa = *(s16x8*)(cA + aoff);
            #pragma unroll
            for (int nt = 0; nt < 8; ++nt) {
                int vd = nt * 16 + l15;
                int boff = vd * 128 + ((ks * 64 + (l >> 4) * 16) ^ ((vd & 7) << 4));
                kacc[mt][nt] = __builtin_amdgcn_mfma_f32_16x16x32_bf16(fa, *(s16x8*)(cVT + boff), kacc[mt][nt], 0, 0, 0);
            }
        }
    }
    __syncthreads();                        // sksf/svsf visible to all

    unsigned short* pb = partial + (size_t)blockIdx.x * 16640;
    #pragma unroll
    for (int mt = 0; mt < 2; ++mt) {
        #pragma unroll
        for (int nt = 0; nt < 8; ++nt) {
            #pragma unroll
            for (int r = 0; r < 4; ++r) {
                int kd = w * 32 + mt * 16 + ((l >> 4) << 2) + r;
                pb[kd * 128 + nt * 16 + l15] = f2bf(kacc[mt][nt][r]);
            }
        }
    }
    if (t < 128) {
        pb[16384 + t] = f2bf(sksf[t] + sksf[128 + t] + sksf[256 + t] + sksf[384 + t]);
    } else {
        int vd = t - 128;
        pb[16512 + vd] = f2bf(svsf[vd] + svsf[128 + vd] + svsf[256 + vd] + svsf[384 + vd]);
    }
}

// ---------------------------------------------------------------------------
// num+combine: accio += (qn @ kvs + sum_v) / (qn . sum_kn + nf)
// ---------------------------------------------------------------------------
__global__ __launch_bounds__(256) void gemm_num_combine(
    const unsigned short* __restrict__ A16,
    const unsigned short* __restrict__ Bth,
    const float* __restrict__ sumv, const float* __restrict__ snk,
    float nf, float* __restrict__ accio, int n,
    const int* __restrict__ ei, int* cntp, int* crowp, int Etot, int e0, int e1,
    int hostGrid)
{
    if (csr_side(hostGrid, ei, cntp, crowp, Etot, e0, e1)) return;

    __shared__ char smem[16384 + 32768];
    char* cA = smem;
    char* cW = smem + 16384;

    const int t = threadIdx.x;
    const int l = t & 63;
    const int w = t >> 6;
    const int l15 = l & 15;
    const int row0 = blockIdx.x * 64;

    #pragma unroll
    for (int i = 0; i < 4; ++i) {
        int f = t + 256 * i;
        int r = f >> 4, c8 = f & 15;
        int gr = row0 + r; if (gr > n - 1) gr = n - 1;
        int byte = r * 256 + ((c8 * 16) ^ ((r & 7) << 4));
        *(s16x8*)(cA + byte) = *(const s16x8*)&A16[(size_t)gr * HID + c8 * 8];
    }
    #pragma unroll
    for (int i = 0; i < 8; ++i) {
        int f = t + 256 * i;
        int nr = f >> 4, c8 = f & 15;
        int byte = nr * 256 + ((c8 * 16) ^ ((nr & 7) << 4));
        *(s16x8*)(cW + byte) = *(const s16x8*)&Bth[(size_t)nr * HID + c8 * 8];
    }
    __syncthreads();

    f32x4 acc[8] = {};
    const int arow = w * 16 + l15;
    #pragma unroll
    for (int ks = 0; ks < 4; ++ks) {
        int aoff = arow * 256 + (((ks * 64) + (l >> 4) * 16) ^ ((arow & 7) << 4));
        s16x8 fa = *(s16x8*)(cA + aoff);
        #pragma unroll
        for (int nt = 0; nt < 8; ++nt) {
            int nr = nt * 16 + l15;
            int boff = nr * 256 + (((ks * 64) + (l >> 4) * 16) ^ ((nr & 7) << 4));
            acc[nt] = __builtin_amdgcn_mfma_f32_16x16x32_bf16(fa, *(s16x8*)(cW + boff), acc[nt], 0, 0, 0);
        }
    }

    const int rbase = row0 + w * 16 + ((l >> 4) << 2);
    const int rtb   = w * 16 + ((l >> 4) << 2);
    float bb[8], skn[8];
    #pragma unroll
    for (int nt = 0; nt < 8; ++nt) {
        bb[nt]  = sumv[nt * 16 + l15];
        skn[nt] = snk[nt * 16 + l15];
    }
    #pragma unroll
    for (int r = 0; r < 4; ++r) {
        int row = rbase + r;
        int rt = rtb + r;
        float p = 0.f;
        #pragma unroll
        for (int nt = 0; nt < 8; ++nt) {
            int byte = rt * 256 + ((2 * (nt * 16 + l15)) ^ ((rt & 7) << 4));
            p += bf2f(*(unsigned short*)(cA + byte)) * skn[nt];
        }
        p += __shfl_xor(p, 1); p += __shfl_xor(p, 2);
        p += __shfl_xor(p, 4); p += __shfl_xor(p, 8);
        float dinv = 1.f / (p + nf);
        if (row < n) {
            #pragma unroll
            for (int nt = 0; nt < 8; ++nt) {
                size_t idx = (size_t)row * HID + nt * 16 + l15;
                accio[idx] += (acc[nt][r] + bb[nt]) * dinv;
            }
        }
    }
}

// ------------------- weight pre-convert (+transpose), hi-only ---------------
struct WConvArgs {
    const float* src[18];
    unsigned short* dh[18];
    int K[18];
};

__global__ void conv_weights(WConvArgs a)
{
    int m = blockIdx.x;
    const float* s = a.src[m];
    unsigned short* dh = a.dh[m];
    int K = a.K[m];
    int tot = 128 * K;
    int slice = (tot + gridDim.y - 1) / gridDim.y;
    int i0 = blockIdx.y * slice;
    int i1 = min(tot, i0 + slice);
    for (int idx = i0 + threadIdx.x; idx < i1; idx += 256) {
        int nn = idx / K, k = idx - nn * K;
        dh[idx] = f2bf(s[(size_t)k * 128 + nn]);
    }
}

// ---- kvs reduce stage A: grid (17, P2G); thread owns an output-quad --------
__global__ __launch_bounds__(256) void reduce_kvs_p2a(
    const unsigned short* __restrict__ partial, int nb,
    float* __restrict__ partial2)
{
    const int oq = blockIdx.x * 256 + threadIdx.x;      // output quad 0..4159
    if (oq >= 4160) return;
    const int g   = blockIdx.y;
    const int per = (nb + P2G - 1) / P2G;
    const int b0  = g * per;
    const int b1  = min(nb, b0 + per);

    float s0 = 0.f, s1 = 0.f, s2 = 0.f, s3 = 0.f;
    int b = b0;
    for (; b + 3 < b1; b += 4) {
        us16x4 u0 = *(const us16x4*)&partial[(size_t)(b + 0) * 16640 + oq * 4];
        us16x4 u1 = *(const us16x4*)&partial[(size_t)(b + 1) * 16640 + oq * 4];
        us16x4 u2 = *(const us16x4*)&partial[(size_t)(b + 2) * 16640 + oq * 4];
        us16x4 u3 = *(const us16x4*)&partial[(size_t)(b + 3) * 16640 + oq * 4];
        s0 += bf2f(u0[0]) + bf2f(u1[0]) + bf2f(u2[0]) + bf2f(u3[0]);
        s1 += bf2f(u0[1]) + bf2f(u1[1]) + bf2f(u2[1]) + bf2f(u3[1]);
        s2 += bf2f(u0[2]) + bf2f(u1[2]) + bf2f(u2[2]) + bf2f(u3[2]);
        s3 += bf2f(u0[3]) + bf2f(u1[3]) + bf2f(u2[3]) + bf2f(u3[3]);
    }
    for (; b < b1; ++b) {
        us16x4 u0 = *(const us16x4*)&partial[(size_t)b * 16640 + oq * 4];
        s0 += bf2f(u0[0]); s1 += bf2f(u0[1]); s2 += bf2f(u0[2]); s3 += bf2f(u0[3]);
    }
    *(f32x4*)&partial2[(size_t)g * 16640 + oq * 4] = (f32x4){s0, s1, s2, s3};
}

// ---- kvs reduce stage B: 65 blocks; sum P2G groups -> kvth + sums ----------
__global__ __launch_bounds__(256) void reduce_kvs_p2b(
    const float* __restrict__ partial2,
    unsigned short* __restrict__ kvth, float* __restrict__ sums)
{
    int o = blockIdx.x * 256 + threadIdx.x;
    if (o >= 16640) return;
    float tot = 0.f;
    #pragma unroll
    for (int g = 0; g < P2G; ++g)
        tot += partial2[(size_t)g * 16640 + o];
    if (o < 16384) {
        int k = o >> 7, nn = o & 127;
        kvth[nn * 128 + k] = f2bf(tot);
    } else {
        sums[o - 16384] = tot;
    }
}

__global__ void rdeg_k(const int* __restrict__ cur, float* __restrict__ rdeg, int n)
{
    int i = blockIdx.x * 256 + threadIdx.x;
    if (i < n) {
        int c = cur[i];
        rdeg[i] = (c > 0) ? rsqrtf((float)c) : 0.f;
    }
}

// ------ fused gather + LN + ELU: 4 nodes/wave (16 lanes/node), 8B loads -----
__global__ __launch_bounds__(256) void gather_ln_elu4(
    const int* __restrict__ cnt, const int* __restrict__ crow,
    const float* __restrict__ rdeg,
    const unsigned char* __restrict__ g, const float* __restrict__ accin,
    const float* __restrict__ gam, const float* __restrict__ bet,
    float* __restrict__ outf, unsigned short* __restrict__ out16, int n)
{
    int node = (int)((blockIdx.x * 256 + threadIdx.x) >> 4);
    int li   = threadIdx.x & 15;
    if (node >= n) return;

    int cn = cnt[node]; if (cn > SLOTS) cn = SLOTS;
    const int* cr = &crow[(size_t)node * SLOTS];
    float rd = rdeg[node];
    const unsigned b8 = (unsigned)li * 8u;
    float4 a0 = *(const float4*)&accin[(size_t)node * HID + li * 8];
    float4 a1 = *(const float4*)&accin[(size_t)node * HID + li * 8 + 4];

    auto acc8 = [&](uint2 U_, float W_) {
        f32x2 pa = __builtin_amdgcn_cvt_pk_f32_fp8((int)U_.x, false);
        f32x2 pb = __builtin_amdgcn_cvt_pk_f32_fp8((int)U_.x, true);
        f32x2 pc = __builtin_amdgcn_cvt_pk_f32_fp8((int)U_.y, false);
        f32x2 pd = __builtin_amdgcn_cvt_pk_f32_fp8((int)U_.y, true);
        a0.x += W_ * pa[0]; a0.y += W_ * pa[1];
        a0.z += W_ * pb[0]; a0.w += W_ * pb[1];
        a1.x += W_ * pc[0]; a1.y += W_ * pc[1];
        a1.z += W_ * pd[0]; a1.w += W_ * pd[1];
    };

    int i = 0;
    for (; i + 3 < cn; i += 4) {
        int   r0 = cr[i],     r1 = cr[i + 1];
        int   r2 = cr[i + 2], r3 = cr[i + 3];
        float w0 = rd * rdeg[r0], w1 = rd * rdeg[r1];
        float w2 = rd * rdeg[r2], w3 = rd * rdeg[r3];
        uint2 u0 = *(const uint2*)&g[(unsigned)r0 * 128u + b8];
        uint2 u1 = *(const uint2*)&g[(unsigned)r1 * 128u + b8];
        uint2 u2 = *(const uint2*)&g[(unsigned)r2 * 128u + b8];
        uint2 u3 = *(const uint2*)&g[(unsigned)r3 * 128u + b8];
        acc8(u0, w0); acc8(u1, w1); acc8(u2, w2); acc8(u3, w3);
    }
    for (; i < cn; ++i) {
        int r0 = cr[i];
        float w0 = rd * rdeg[r0];
        uint2 u0 = *(const uint2*)&g[(unsigned)r0 * 128u + b8];
        acc8(u0, w0);
    }

    float sm = a0.x + a0.y + a0.z + a0.w + a1.x + a1.y + a1.z + a1.w;
    float ss = a0.x * a0.x + a0.y * a0.y + a0.z * a0.z + a0.w * a0.w
             + a1.x * a1.x + a1.y * a1.y + a1.z * a1.z + a1.w * a1.w;
    #pragma unroll
    for (int o = 8; o; o >>= 1) { sm += __shfl_xor(sm, o); ss += __shfl_xor(ss, o); }
    float mu  = sm * (1.f / 128.f);
    float var = ss * (1.f / 128.f) - mu * mu;
    float rs  = rsqrtf(var + EPS);
    float4 gm0 = *(const float4*)&gam[li * 8];
    float4 gm1 = *(const float4*)&gam[li * 8 + 4];
    float4 bt0 = *(const float4*)&bet[li * 8];
    float4 bt1 = *(const float4*)&bet[li * 8 + 4];
    float y0 = eluf((a0.x - mu) * rs * gm0.x + bt0.x);
    float y1 = eluf((a0.y - mu) * rs * gm0.y + bt0.y);
    float y2 = eluf((a0.z - mu) * rs * gm0.z + bt0.z);
    float y3 = eluf((a0.w - mu) * rs * gm0.w + bt0.w);
    float y4 = eluf((a1.x - mu) * rs * gm1.x + bt1.x);
    float y5 = eluf((a1.y - mu) * rs * gm1.y + bt1.y);
    float y6 = eluf((a1.z - mu) * rs * gm1.z + bt1.z);
    float y7 = eluf((a1.w - mu) * rs * gm1.w + bt1.w);
    if (out16) {
        us16x4 o0 = (us16x4){f2bf(y0), f2bf(y1), f2bf(y2), f2bf(y3)};
        us16x4 o1 = (us16x4){f2bf(y4), f2bf(y5), f2bf(y6), f2bf(y7)};
        *(us16x4*)&out16[(size_t)node * HID + li * 8]     = o0;
        *(us16x4*)&out16[(size_t)node * HID + li * 8 + 4] = o1;
    } else {
        *(float4*)&outf[(size_t)node * HID + li * 8]     = make_float4(y0, y1, y2, y3);
        *(float4*)&outf[(size_t)node * HID + li * 8 + 4] = make_float4(y4, y5, y6, y7);
    }
}

// ---------------------------------------------------------------------------
extern "C" void kernel_launch(void* const* d_in, const int* in_sizes, int n_in,
                              void* d_out, int out_size, void* d_ws, size_t ws_size,
                              hipStream_t stream)
{
    const float* x      = (const float*)d_in[0];
    const int*   ei     = (const int*)  d_in[1];
    const float* mlp_W0 = (const float*)d_in[2];
    const float* mlp_b0 = (const float*)d_in[3];
    const float* mlp_W  = (const float*)d_in[4];
    const float* mlp_b  = (const float*)d_in[5];
    const float* bn_g   = (const float*)d_in[6];
    const float* bn_b   = (const float*)d_in[7];
    const float* bn_m   = (const float*)d_in[8];
    const float* bn_v   = (const float*)d_in[9];
    const float* Wq = (const float*)d_in[10]; const float* bq = (const float*)d_in[11];
    const float* Wk = (const float*)d_in[12]; const float* bk = (const float*)d_in[13];
    const float* Wv = (const float*)d_in[14]; const float* bv = (const float*)d_in[15];
    const float* Wg = (const float*)d_in[16]; const float* bg = (const float*)d_in[17];
    const float* Wr = (const float*)d_in[18]; const float* br = (const float*)d_in[19];
    const float* ln_g = (const float*)d_in[20];
    const float* ln_b = (const float*)d_in[21];

    const int N = in_sizes[0] / INC;
    const int E = in_sizes[1] / 2;
    const size_t P = (size_t)N * HID;
    const int gemmGrid = (N + 63) / 64;

    // workspace layout
    unsigned short* partial = (unsigned short*)d_ws;            // max(gemmGrid*16640, P) bf16
    size_t partUS = (size_t)gemmGrid * 16640;
    if (partUS < P) partUS = P;
    unsigned short* h16  = partial + partUS;                    // P bf16
    unsigned short* qb16 = h16 + P;                             // P bf16
    unsigned char*  gb8  = (unsigned char*)(qb16 + P);          // P fp8
    float* kvs  = (float*)(gb8 + P);                            // 256 f
    float* partial2 = kvs + 256;                                // P2G*16640 f32
    int*   crow = (int*)(partial2 + (size_t)P2G * 16640);       // N*SLOTS
    int*   cnt  = crow + (size_t)N * SLOTS;                     // N
    float* rdeg = (float*)(cnt + N);                            // N
    unsigned short* wt = (unsigned short*)(rdeg + N);

    // MLP scratch (dead before first partial/qb16 use)
    unsigned short* mlpA = partial;
    unsigned short* mlpB = qb16;

    unsigned short* WTh[18];
    int Ks[18];
    size_t woff = 0;
    for (int m = 0; m < 18; ++m) {
        int K = (m == 0) ? INC : HID;
        Ks[m] = K;
        WTh[m] = wt + woff;           woff += (size_t)128 * K;
    }
    unsigned short* kvth = wt + woff; woff += 16384;
    float* acc = (float*)d_out;

    const int gw4Grid  = (N + 15) / 16;
    const int nodeGrid = (N + 255) / 256;

    // CSR chunk bounds: 5 chunks hidden under MLP0/1/2, qkvgr0, num_combine0
    int eb[6];
    for (int i = 0; i <= 5; ++i) eb[i] = (int)(((long long)E * i) / 5);
    auto cb = [&](int i) { return (eb[i + 1] - eb[i] + 255) / 256; };

    // --- weight pre-convert (hi-only, transposed) ---
    WConvArgs wa;
    const float* srcs[18];
    srcs[0] = mlp_W0; srcs[1] = mlp_W; srcs[2] = mlp_W + (size_t)HID * HID;
    for (int l = 0; l < NLAYER; ++l) {
        const size_t wo = (size_t)l * HID * HID;
        srcs[3 + l * 5 + 0] = Wq + wo;
        srcs[3 + l * 5 + 1] = Wk + wo;
        srcs[3 + l * 5 + 2] = Wv + wo;
        srcs[3 + l * 5 + 3] = Wg + wo;
        srcs[3 + l * 5 + 4] = Wr + wo;
    }
    for (int m = 0; m < 18; ++m) {
        wa.src[m] = srcs[m]; wa.dh[m] = WTh[m]; wa.K[m] = Ks[m];
    }
    conv_weights<<<dim3(18, 8), 256, 0, stream>>>(wa);

    hipMemsetAsync(cnt, 0, (size_t)N * sizeof(int), stream);

    // --- MLP (each hosts a CSR chunk) ---
    gemm_mlp<INC, true><<<gemmGrid + cb(0), 256, 0, stream>>>(x, nullptr, WTh[0], mlp_b0,
        bn_g, bn_b, bn_m, bn_v, mlpA, N, ei, cnt, crow, E, eb[0], eb[1], gemmGrid);
    gemm_mlp<HID, false><<<gemmGrid + cb(1), 256, 0, stream>>>(nullptr, mlpA, WTh[1], mlp_b,
        bn_g + HID, bn_b + HID, bn_m + HID, bn_v + HID, mlpB, N,
        ei, cnt, crow, E, eb[1], eb[2], gemmGrid);
    gemm_mlp<HID, false><<<gemmGrid + cb(2), 256, 0, stream>>>(nullptr, mlpB, WTh[2], mlp_b + HID,
        bn_g + 2 * HID, bn_b + 2 * HID, bn_m + 2 * HID, bn_v + 2 * HID, h16, N,
        ei, cnt, crow, E, eb[2], eb[3], gemmGrid);

    // --- TransConv layers ---
    for (int l = 0; l < NLAYER; ++l) {
        const int bo = l * HID;
        const bool l0 = (l == 0);

        QKVGRArgs qa;
        for (int m = 0; m < 5; ++m) qa.wh[m] = WTh[3 + l * 5 + m];
        qa.bias[0] = bq + bo; qa.bias[1] = bk + bo; qa.bias[2] = bv + bo;
        qa.bias[3] = bg + bo; qa.bias[4] = br + bo;

        // h16 -> qn, g, acc(r+res), partial kvs  (layer 0 hosts CSR chunk 3)
        fused_qkvgr<<<gemmGrid + (l0 ? cb(3) : 0), 256, 0, stream>>>(h16, qa,
            qb16, gb8, acc, partial, N,
            ei, cnt, crow, E, l0 ? eb[3] : 0, l0 ? eb[4] : 0, gemmGrid);

        // kvs = sum of per-block partials (two-stage, parallel)
        reduce_kvs_p2a<<<dim3(17, P2G), 256, 0, stream>>>(partial, gemmGrid, partial2);
        reduce_kvs_p2b<<<65, 256, 0, stream>>>(partial2, kvth, kvs);

        // acc += (qn @ kvs + sum_v) / (qn . sum_kn + N)  (layer 0 hosts chunk 4)
        gemm_num_combine<<<gemmGrid + (l0 ? cb(4) : 0), 256, 0, stream>>>(qb16, kvth,
            kvs + 128, kvs, (float)N, acc, N,
            ei, cnt, crow, E, l0 ? eb[4] : 0, l0 ? eb[5] : 0, gemmGrid);

        // rdeg after the last CSR chunk, before the first gather
        if (l0) rdeg_k<<<nodeGrid, 256, 0, stream>>>(cnt, rdeg, N);

        // fused gather (fp8 g, 4 nodes/wave) + LN + ELU
        bool last = (l == NLAYER - 1);
        gather_ln_elu4<<<gw4Grid, 256, 0, stream>>>(cnt, crow, rdeg,
            gb8, acc, ln_g + bo, ln_b + bo,
            last ? acc : nullptr, last ? nullptr : h16, N);
    }
}